// Round 1
// baseline (327.440 us; speedup 1.0000x reference)
//
#include <hip/hip_runtime.h>

#define NROWS 8
#define NPIX  262144          // 512*512
#define K1_BPR 256            // blocks per row, compute pass (1024 px/block)
#define K3_BPR 64             // blocks per row, refine/collect (4096 px/block)
#define CAP   16384           // candidate buffer capacity per row

struct Ctrl {
  unsigned int prefix8[NROWS];
  unsigned int kRem1[NROWS];
  unsigned int prefix16[NROWS];
  unsigned int kRem2[NROWS];
  unsigned int candCount[NROWS];
  unsigned long long selT;
  unsigned long long tTotal;
  double selL3;
  unsigned int kVal;
};

// monotonic float->uint map (ascending float == ascending uint)
__device__ __forceinline__ unsigned int fkey(float x){
  unsigned int u = __float_as_uint(x);
  return (u & 0x80000000u) ? ~u : (u | 0x80000000u);
}

__device__ __forceinline__ void softmax2(float a0, float a1,
    float& lp0, float& lp1, float& p0, float& p1){
  float m  = fmaxf(a0, a1);
  float z0 = a0 - m, z1 = a1 - m;      // one of them is 0
  float e0 = __expf(z0), e1 = __expf(z1);
  float s  = e0 + e1;                  // in [1,2]
  float ls = __logf(s);
  float rs = __builtin_amdgcn_rcpf(s);
  lp0 = z0 - ls; lp1 = z1 - ls;
  p0  = e0 * rs; p1  = e1 * rs;
}

__device__ __forceinline__ float focal2(float tt, float lp0, float lp1,
                                        float p0, float p1){
  float q1 = 1.0f - p1, q0 = 1.0f - p0;
  return -(tt * q1 * q1 * lp1) - ((1.0f - tt) * q0 * q0 * lp0);
}

__global__ __launch_bounds__(256) void k_compute(
    const float* __restrict__ in1, const float* __restrict__ in2,
    const float* __restrict__ in3, const int* __restrict__ tgt,
    const float* __restrict__ kdwp,
    unsigned int* __restrict__ keys, float* __restrict__ l3out,
    unsigned int* __restrict__ hist0, Ctrl* __restrict__ ctrl)
{
  __shared__ unsigned int h[256];
  const int t = threadIdx.x;
  h[t] = 0;
  __syncthreads();

  const int blk   = blockIdx.x;
  const int row   = blk / K1_BPR;
  const int chunk = (blk % K1_BPR) * (NPIX / K1_BPR);
  const int base  = chunk + 4 * t;         // 4 consecutive pixels per thread
  const float kdw = *kdwp;
  const float w1  = (float)(1.0 - (double)kdw);

  const size_t ro2 = (size_t)row * 2 * NPIX;   // input row offset (2 channels)
  const size_t ro1 = (size_t)row * NPIX;

  float4 x10 = *(const float4*)(in1 + ro2 + base);
  float4 x11 = *(const float4*)(in1 + ro2 + NPIX + base);
  float4 x20 = *(const float4*)(in2 + ro2 + base);
  float4 x21 = *(const float4*)(in2 + ro2 + NPIX + base);
  float4 x30 = *(const float4*)(in3 + ro2 + base);
  float4 x31 = *(const float4*)(in3 + ro2 + NPIX + base);
  int4   tg  = *(const int4*)(tgt + ro1 + base);

  float a10[4] = {x10.x, x10.y, x10.z, x10.w};
  float a11[4] = {x11.x, x11.y, x11.z, x11.w};
  float a20[4] = {x20.x, x20.y, x20.z, x20.w};
  float a21[4] = {x21.x, x21.y, x21.z, x21.w};
  float a30[4] = {x30.x, x30.y, x30.z, x30.w};
  float a31[4] = {x31.x, x31.y, x31.z, x31.w};
  int   tgv[4] = {tg.x, tg.y, tg.z, tg.w};

  unsigned int kv[4]; float l3v[4];
  int myT = 0;
  #pragma unroll
  for (int j = 0; j < 4; ++j){
    float tt = (float)tgv[j]; myT += tgv[j];
    float lp10, lp11, p10, p11; softmax2(a10[j], a11[j], lp10, lp11, p10, p11);
    float lp20, lp21, p20, p21; softmax2(a20[j], a21[j], lp20, lp21, p20, p21);
    float lp30, lp31, p30, p31; softmax2(a30[j], a31[j], lp30, lp31, p30, p31);
    float l1 = focal2(tt, lp10, lp11, p10, p11);
    float l2 = focal2(tt, lp20, lp21, p20, p21);
    float l3 = focal2(tt, lp30, lp31, p30, p31);
    float kdl12 = p10 * (lp10 - lp20) + p11 * (lp11 - lp21);
    float kdl21 = p20 * (lp20 - lp10) + p21 * (lp21 - lp11);
    float loss  = w1 * (l1 + l2 + l3) + kdw * (kdl12 + kdl21);
    kv[j]  = fkey(loss);
    l3v[j] = l3;
  }
  *(uint4*)(keys + ro1 + base)   = make_uint4(kv[0], kv[1], kv[2], kv[3]);
  *(float4*)(l3out + ro1 + base) = make_float4(l3v[0], l3v[1], l3v[2], l3v[3]);

  // wave-aggregated LDS histogram of key[31:24] (exponent bits concentrate ->
  // plain per-lane LDS atomics would serialize heavily)
  const int lane = t & 63;
  #pragma unroll
  for (int j = 0; j < 4; ++j){
    unsigned bin = kv[j] >> 24;
    unsigned long long rem = ~0ull;
    while (rem){
      int lead = __ffsll(rem) - 1;
      unsigned leadBin = (unsigned)__shfl((int)bin, lead);
      unsigned long long same = __ballot(bin == leadBin);
      if (lane == lead) atomicAdd(&h[leadBin], (unsigned)__popcll(same));
      rem &= ~same;
    }
  }

  // total targets sum
  int wsum = myT;
  #pragma unroll
  for (int o = 32; o; o >>= 1) wsum += __shfl_down(wsum, o);
  if (lane == 0) atomicAdd(&ctrl->tTotal, (unsigned long long)wsum);

  __syncthreads();
  unsigned hv = h[t];
  if (hv) atomicAdd(&hist0[row * 256 + t], hv);
}

__global__ __launch_bounds__(256) void k_scan(int level,
    const unsigned int* __restrict__ hist, Ctrl* ctrl,
    const float* __restrict__ frp)
{
  __shared__ unsigned int cum[256];
  const int t = threadIdx.x;
  const unsigned int k0 =
      (unsigned int)((1.0 - (double)(*frp)) * (double)NPIX);   // 209715
  if (level == 0 && t == 0) ctrl->kVal = k0;
  for (int row = 0; row < NROWS; ++row){
    unsigned int v = hist[row * 256 + t];
    cum[t] = v;
    __syncthreads();
    for (int off = 1; off < 256; off <<= 1){
      unsigned int add = (t >= off) ? cum[t - off] : 0u;
      __syncthreads();
      cum[t] += add;
      __syncthreads();
    }
    unsigned int kRem = (level == 0) ? k0 : ctrl->kRem1[row];
    unsigned int inc = cum[t], exc = inc - v;
    if (exc < kRem && inc >= kRem){            // exactly one thread
      if (level == 0){
        ctrl->prefix8[row] = (unsigned)t;
        ctrl->kRem1[row]   = kRem - exc;
      } else {
        ctrl->prefix16[row] = (ctrl->prefix8[row] << 8) | (unsigned)t;
        ctrl->kRem2[row]    = kRem - exc;
      }
    }
    __syncthreads();
  }
}

__global__ __launch_bounds__(256) void k_refine(
    const unsigned int* __restrict__ keys, const Ctrl* __restrict__ ctrl,
    unsigned int* __restrict__ hist1)
{
  __shared__ unsigned int h[256];
  const int t = threadIdx.x;
  h[t] = 0;
  __syncthreads();
  const int row   = blockIdx.x / K3_BPR;
  const int chunk = (blockIdx.x % K3_BPR) * (NPIX / K3_BPR);
  const unsigned pfx = ctrl->prefix8[row];
  const uint4* kp = (const uint4*)(keys + (size_t)row * NPIX + chunk);
  #pragma unroll
  for (int it = 0; it < 4; ++it){
    uint4 kvv = kp[it * 256 + t];
    unsigned a[4] = {kvv.x, kvv.y, kvv.z, kvv.w};
    #pragma unroll
    for (int j = 0; j < 4; ++j)
      if ((a[j] >> 24) == pfx) atomicAdd(&h[(a[j] >> 16) & 255], 1u);
  }
  __syncthreads();
  unsigned hv = h[t];
  if (hv) atomicAdd(&hist1[row * 256 + t], hv);
}

__global__ __launch_bounds__(256) void k_collect(
    const unsigned int* __restrict__ keys, const float* __restrict__ l3,
    const int* __restrict__ tgt, Ctrl* ctrl, uint4* __restrict__ cand, int cap)
{
  const int t    = threadIdx.x;
  const int lane = t & 63;
  const int row   = blockIdx.x / K3_BPR;
  const int chunk = (blockIdx.x % K3_BPR) * (NPIX / K3_BPR);
  const unsigned pfx16 = ctrl->prefix16[row];
  const size_t ro = (size_t)row * NPIX;
  float sL3 = 0.0f; int sT = 0;
  #pragma unroll
  for (int it = 0; it < 4; ++it){
    int base = chunk + it * 1024 + 4 * t;
    uint4  kvv = *(const uint4*)(keys + ro + base);
    float4 lv  = *(const float4*)(l3  + ro + base);
    int4   tv  = *(const int4*)(tgt + ro + base);
    unsigned ka[4] = {kvv.x, kvv.y, kvv.z, kvv.w};
    float    la[4] = {lv.x, lv.y, lv.z, lv.w};
    int      ta[4] = {tv.x, tv.y, tv.z, tv.w};
    #pragma unroll
    for (int j = 0; j < 4; ++j){
      unsigned hi = ka[j] >> 16;
      if (hi < pfx16){ sL3 += la[j]; sT += ta[j]; }
      bool app = (hi == pfx16);
      unsigned long long mb = __ballot(app);
      if (mb){
        int lead = __ffsll(mb) - 1;
        unsigned basePos = 0;
        if (lane == lead)
          basePos = atomicAdd(&ctrl->candCount[row], (unsigned)__popcll(mb));
        basePos = (unsigned)__shfl((int)basePos, lead);
        if (app){
          unsigned off = basePos + (unsigned)__popcll(mb & ((1ull << lane) - 1ull));
          if (off < (unsigned)cap)
            cand[(size_t)row * cap + off] =
                make_uint4(ka[j], (unsigned)(base + j),
                           __float_as_uint(la[j]), (unsigned)ta[j]);
        }
      }
    }
  }
  #pragma unroll
  for (int o = 32; o; o >>= 1){ sL3 += __shfl_down(sL3, o); sT += __shfl_down(sT, o); }
  if (lane == 0){
    atomicAdd(&ctrl->selL3, (double)sL3);
    atomicAdd(&ctrl->selT, (unsigned long long)(unsigned int)sT);
  }
}

__global__ __launch_bounds__(256) void k_resolve(
    const uint4* __restrict__ cand, int cap, Ctrl* ctrl)
{
  __shared__ unsigned int h[256];
  __shared__ unsigned int selBin, selRem;
  __shared__ float wl[4];
  __shared__ int   wt[4];
  const int t   = threadIdx.x;
  const int row = blockIdx.x;
  unsigned cnt  = ctrl->candCount[row]; if (cnt > (unsigned)cap) cnt = (unsigned)cap;
  unsigned kRem = ctrl->kRem2[row];     if (kRem > cnt) kRem = cnt;
  const uint4* cb = cand + (size_t)row * cap;

  // pass 1: bits [15:8]
  h[t] = 0; __syncthreads();
  for (unsigned i = t; i < cnt; i += 256) atomicAdd(&h[(cb[i].x >> 8) & 255], 1u);
  __syncthreads();
  if (t == 0){
    selBin = 0; selRem = 0;
    unsigned c2 = 0;
    for (int b = 0; b < 256; ++b){
      unsigned nb = c2 + h[b];
      if (c2 < kRem && nb >= kRem){ selBin = (unsigned)b; selRem = kRem - c2; break; }
      c2 = nb;
    }
  }
  __syncthreads();
  unsigned b1 = selBin, kr = selRem;
  __syncthreads();

  // pass 2: bits [7:0] among b1 matches
  h[t] = 0; __syncthreads();
  for (unsigned i = t; i < cnt; i += 256){
    unsigned key = cb[i].x;
    if (((key >> 8) & 255) == b1) atomicAdd(&h[key & 255], 1u);
  }
  __syncthreads();
  if (t == 0){
    selBin = 0; selRem = 0;
    unsigned c2 = 0;
    for (int b = 0; b < 256; ++b){
      unsigned nb = c2 + h[b];
      if (c2 < kr && nb >= kr){ selBin = (unsigned)b; selRem = kr - c2; break; }
      c2 = nb;
    }
  }
  __syncthreads();
  const unsigned T     = (ctrl->prefix16[row] << 16) | (b1 << 8) | selBin;
  const unsigned mNeed = selRem;

  float sL3 = 0.0f; int sT = 0;
  for (unsigned i = t; i < cnt; i += 256){
    uint4 e = cb[i];
    bool take = false;
    if (e.x < T) take = true;
    else if (e.x == T){
      // stable-argsort tie-break: first mNeed by original index
      unsigned rank = 0;
      for (unsigned j2 = 0; j2 < cnt; ++j2){
        uint4 f = cb[j2];
        rank += (f.x == T && f.y < e.y) ? 1u : 0u;
      }
      take = (rank < mNeed);
    }
    if (take){ sL3 += __uint_as_float(e.z); sT += (int)e.w; }
  }
  const int lane = t & 63, wid = t >> 6;
  #pragma unroll
  for (int o = 32; o; o >>= 1){ sL3 += __shfl_down(sL3, o); sT += __shfl_down(sT, o); }
  if (lane == 0){ wl[wid] = sL3; wt[wid] = sT; }
  __syncthreads();
  if (t == 0){
    float a  = wl[0] + wl[1] + wl[2] + wl[3];
    int   b2 = wt[0] + wt[1] + wt[2] + wt[3];
    atomicAdd(&ctrl->selL3, (double)a);
    atomicAdd(&ctrl->selT, (unsigned long long)(unsigned)b2);
  }
}

__global__ void k_final(const Ctrl* __restrict__ ctrl, float* __restrict__ out){
  if (threadIdx.x == 0 && blockIdx.x == 0){
    double lo = ctrl->selL3 / ((double)NROWS * (double)ctrl->kVal);
    double ls = (double)ctrl->selT / (double)ctrl->tTotal;
    out[0] = (float)lo;
    out[1] = (float)ls;
  }
}

extern "C" void kernel_launch(void* const* d_in, const int* in_sizes, int n_in,
                              void* d_out, int out_size, void* d_ws, size_t ws_size,
                              hipStream_t stream)
{
  const float* in1  = (const float*)d_in[0];
  const float* in2  = (const float*)d_in[1];
  const float* in3  = (const float*)d_in[2];
  const int*   tgt  = (const int*)d_in[3];
  const float* frp  = (const float*)d_in[4];
  const float* kdwp = (const float*)d_in[5];
  float* out = (float*)d_out;
  char*  ws  = (char*)d_ws;

  const size_t off_keys = 0;
  const size_t off_l3   = (size_t)NROWS * NPIX * 4;              // 8 MB
  const size_t off_h0   = off_l3 + (size_t)NROWS * NPIX * 4;     // 16 MB
  const size_t off_h1   = off_h0 + (size_t)NROWS * 256 * 4;
  const size_t off_ctrl = off_h1 + (size_t)NROWS * 256 * 4;
  const size_t off_cand = (off_ctrl + sizeof(Ctrl) + 255) & ~(size_t)255;

  int cap = CAP;
  if (ws_size < off_cand + (size_t)NROWS * cap * 16){
    size_t avail = (ws_size > off_cand) ? (ws_size - off_cand) / ((size_t)NROWS * 16) : 0;
    cap = (int)avail;
  }

  unsigned int* keys = (unsigned int*)(ws + off_keys);
  float*        l3   = (float*)(ws + off_l3);
  unsigned int* h0   = (unsigned int*)(ws + off_h0);
  unsigned int* h1   = (unsigned int*)(ws + off_h1);
  Ctrl*         ctrl = (Ctrl*)(ws + off_ctrl);
  uint4*        cand = (uint4*)(ws + off_cand);

  hipMemsetAsync(ws + off_h0, 0, off_cand - off_h0, stream);
  k_compute<<<NROWS * K1_BPR, 256, 0, stream>>>(in1, in2, in3, tgt, kdwp,
                                                keys, l3, h0, ctrl);
  k_scan<<<1, 256, 0, stream>>>(0, h0, ctrl, frp);
  k_refine<<<NROWS * K3_BPR, 256, 0, stream>>>(keys, ctrl, h1);
  k_scan<<<1, 256, 0, stream>>>(1, h1, ctrl, frp);
  k_collect<<<NROWS * K3_BPR, 256, 0, stream>>>(keys, l3, tgt, ctrl, cand, cap);
  k_resolve<<<NROWS, 256, 0, stream>>>(cand, cap, ctrl);
  k_final<<<1, 1, 0, stream>>>(ctrl, out);
}

// Round 2
// 140.883 us; speedup vs baseline: 2.3242x; 2.3242x over previous
//
#include <hip/hip_runtime.h>

#define NROWS 8
#define NPIX  262144          // 512*512
#define K1_BPR 256            // compute: 1024 px/block, grid 2048
#define KR_BPR 64             // refine : 4096 px/block, grid 512
#define KC_BPR 128            // collect: 2048 px/block, grid 1024
#define KC_BUF 2048           // LDS candidate buffer (= px/block, always safe)
#define CAP   16384           // global candidate buffer capacity per row

struct Ctrl {
  unsigned int prefix8[NROWS];
  unsigned int kRem1[NROWS];
  unsigned int prefix16[NROWS];
  unsigned int kRem2[NROWS];
  unsigned int candCount[NROWS];
  unsigned long long selT;      // resolve's contribution
  double selL3;                 // resolve's contribution
  unsigned int kVal;
};

// monotonic float->uint map (ascending float == ascending uint)
__device__ __forceinline__ unsigned int fkey(float x){
  unsigned int u = __float_as_uint(x);
  return (u & 0x80000000u) ? ~u : (u | 0x80000000u);
}

// binary softmax with a single exp: z_min = -|a1-a0|, z_max = 0
__device__ __forceinline__ void softmax2(float a0, float a1,
    float& lp0, float& lp1, float& p0, float& p1){
  float d  = a1 - a0;
  float ad = -fabsf(d);
  float e  = __expf(ad);
  float s  = 1.0f + e;                  // in [1,2]
  float ls = __logf(s);
  float rs = __builtin_amdgcn_rcpf(s);
  float lpM = -ls,     lpm = ad - ls;
  float pM  = rs,      pm  = e * rs;
  bool g = (d >= 0.0f);                 // class1 is the max
  lp1 = g ? lpM : lpm;  lp0 = g ? lpm : lpM;
  p1  = g ? pM  : pm;   p0  = g ? pm  : pM;
}

__device__ __forceinline__ float focal2(float tt, float lp0, float lp1,
                                        float p0, float p1){
  float q1 = 1.0f - p1, q0 = 1.0f - p0;
  return -(tt * q1 * q1 * lp1) - ((1.0f - tt) * q0 * q0 * lp0);
}

__global__ __launch_bounds__(256) void k_compute(
    const float* __restrict__ in1, const float* __restrict__ in2,
    const float* __restrict__ in3, const int* __restrict__ tgt,
    const float* __restrict__ kdwp,
    unsigned int* __restrict__ keys, float* __restrict__ l3out,
    unsigned int* __restrict__ hist0, unsigned int* __restrict__ partialT)
{
  __shared__ unsigned int h[256];
  __shared__ int wt[4];
  const int t = threadIdx.x;
  h[t] = 0;
  __syncthreads();

  const int blk   = blockIdx.x;
  const int row   = blk / K1_BPR;
  const int chunk = (blk % K1_BPR) * (NPIX / K1_BPR);
  const int base  = chunk + 4 * t;
  const float kdw = *kdwp;
  const float w1  = (float)(1.0 - (double)kdw);

  const size_t ro2 = (size_t)row * 2 * NPIX;
  const size_t ro1 = (size_t)row * NPIX;

  float4 x10 = *(const float4*)(in1 + ro2 + base);
  float4 x11 = *(const float4*)(in1 + ro2 + NPIX + base);
  float4 x20 = *(const float4*)(in2 + ro2 + base);
  float4 x21 = *(const float4*)(in2 + ro2 + NPIX + base);
  float4 x30 = *(const float4*)(in3 + ro2 + base);
  float4 x31 = *(const float4*)(in3 + ro2 + NPIX + base);
  int4   tg  = *(const int4*)(tgt + ro1 + base);

  float a10[4] = {x10.x, x10.y, x10.z, x10.w};
  float a11[4] = {x11.x, x11.y, x11.z, x11.w};
  float a20[4] = {x20.x, x20.y, x20.z, x20.w};
  float a21[4] = {x21.x, x21.y, x21.z, x21.w};
  float a30[4] = {x30.x, x30.y, x30.z, x30.w};
  float a31[4] = {x31.x, x31.y, x31.z, x31.w};
  int   tgv[4] = {tg.x, tg.y, tg.z, tg.w};

  unsigned int kv[4]; float l3v[4];
  int myT = 0;
  #pragma unroll
  for (int j = 0; j < 4; ++j){
    float tt = (float)tgv[j]; myT += tgv[j];
    float lp10, lp11, p10, p11; softmax2(a10[j], a11[j], lp10, lp11, p10, p11);
    float lp20, lp21, p20, p21; softmax2(a20[j], a21[j], lp20, lp21, p20, p21);
    float lp30, lp31, p30, p31; softmax2(a30[j], a31[j], lp30, lp31, p30, p31);
    float l1 = focal2(tt, lp10, lp11, p10, p11);
    float l2 = focal2(tt, lp20, lp21, p20, p21);
    float l3 = focal2(tt, lp30, lp31, p30, p31);
    float kdl12 = p10 * (lp10 - lp20) + p11 * (lp11 - lp21);
    float kdl21 = p20 * (lp20 - lp10) + p21 * (lp21 - lp11);
    float loss  = w1 * (l1 + l2 + l3) + kdw * (kdl12 + kdl21);
    kv[j]  = fkey(loss);
    // pack target into sign bit (focal loss >= 0) so collect needn't re-read tgt
    l3v[j] = __uint_as_float(__float_as_uint(l3) | ((unsigned)tgv[j] << 31));
  }
  *(uint4*)(keys + ro1 + base)   = make_uint4(kv[0], kv[1], kv[2], kv[3]);
  *(float4*)(l3out + ro1 + base) = make_float4(l3v[0], l3v[1], l3v[2], l3v[3]);

  // wave-aggregated LDS histogram of key[31:24] (exponent bits concentrate)
  const int lane = t & 63;
  #pragma unroll
  for (int j = 0; j < 4; ++j){
    unsigned bin = kv[j] >> 24;
    unsigned long long rem = ~0ull;
    while (rem){
      int lead = __ffsll(rem) - 1;
      unsigned leadBin = (unsigned)__shfl((int)bin, lead);
      unsigned long long same = __ballot(bin == leadBin);
      if (lane == lead) atomicAdd(&h[leadBin], (unsigned)__popcll(same));
      rem &= ~same;
    }
  }

  // block-level target sum -> plain store (no contended atomics)
  int wsum = myT;
  #pragma unroll
  for (int o = 32; o; o >>= 1) wsum += __shfl_down(wsum, o);
  if (lane == 0) wt[t >> 6] = wsum;

  __syncthreads();
  unsigned hv = h[t];
  if (hv) atomicAdd(&hist0[row * 256 + t], hv);
  if (t == 0) partialT[blk] = (unsigned)(wt[0] + wt[1] + wt[2] + wt[3]);
}

__global__ __launch_bounds__(256) void k_scan(int level,
    const unsigned int* __restrict__ hist, Ctrl* ctrl,
    const float* __restrict__ frp)
{
  __shared__ unsigned int cum[256];
  const int t = threadIdx.x;
  const unsigned int k0 =
      (unsigned int)((1.0 - (double)(*frp)) * (double)NPIX);   // 209715
  if (level == 0 && t == 0) ctrl->kVal = k0;
  for (int row = 0; row < NROWS; ++row){
    unsigned int v = hist[row * 256 + t];
    cum[t] = v;
    __syncthreads();
    for (int off = 1; off < 256; off <<= 1){
      unsigned int add = (t >= off) ? cum[t - off] : 0u;
      __syncthreads();
      cum[t] += add;
      __syncthreads();
    }
    unsigned int kRem = (level == 0) ? k0 : ctrl->kRem1[row];
    unsigned int inc = cum[t], exc = inc - v;
    if (exc < kRem && inc >= kRem){            // exactly one thread
      if (level == 0){
        ctrl->prefix8[row] = (unsigned)t;
        ctrl->kRem1[row]   = kRem - exc;
      } else {
        ctrl->prefix16[row] = (ctrl->prefix8[row] << 8) | (unsigned)t;
        ctrl->kRem2[row]    = kRem - exc;
      }
    }
    __syncthreads();
  }
}

__global__ __launch_bounds__(256) void k_refine(
    const unsigned int* __restrict__ keys, const Ctrl* __restrict__ ctrl,
    unsigned int* __restrict__ hist1)
{
  __shared__ unsigned int h[256];
  const int t = threadIdx.x;
  h[t] = 0;
  __syncthreads();
  const int row   = blockIdx.x / KR_BPR;
  const int chunk = (blockIdx.x % KR_BPR) * (NPIX / KR_BPR);
  const unsigned pfx = ctrl->prefix8[row];
  const uint4* kp = (const uint4*)(keys + (size_t)row * NPIX + chunk);
  #pragma unroll
  for (int it = 0; it < 4; ++it){
    uint4 kvv = kp[it * 256 + t];
    unsigned a[4] = {kvv.x, kvv.y, kvv.z, kvv.w};
    #pragma unroll
    for (int j = 0; j < 4; ++j)
      if ((a[j] >> 24) == pfx) atomicAdd(&h[(a[j] >> 16) & 255], 1u);
  }
  __syncthreads();
  unsigned hv = h[t];
  if (hv) atomicAdd(&hist1[row * 256 + t], hv);
}

__global__ __launch_bounds__(256) void k_collect(
    const unsigned int* __restrict__ keys, const float* __restrict__ l3,
    Ctrl* ctrl, uint4* __restrict__ cand, int cap,
    float* __restrict__ partialL3, unsigned int* __restrict__ partialT2)
{
  __shared__ uint4 buf[KC_BUF];            // 32 KB candidate staging
  __shared__ unsigned cnt, basePos;
  __shared__ float wl[4];
  __shared__ int   wt[4];
  const int t    = threadIdx.x;
  const int lane = t & 63, wid = t >> 6;
  const int blk   = blockIdx.x;
  const int row   = blk / KC_BPR;
  const int chunk = (blk % KC_BPR) * (NPIX / KC_BPR);
  const unsigned pfx16 = ctrl->prefix16[row];
  const size_t ro = (size_t)row * NPIX;
  if (t == 0) cnt = 0;
  __syncthreads();

  float sL3 = 0.0f; int sT = 0;
  #pragma unroll
  for (int it = 0; it < 2; ++it){
    int base = chunk + it * 1024 + 4 * t;
    uint4  kvv = *(const uint4*)(keys + ro + base);
    float4 lv  = *(const float4*)(l3  + ro + base);
    unsigned ka[4] = {kvv.x, kvv.y, kvv.z, kvv.w};
    float    la[4] = {lv.x, lv.y, lv.z, lv.w};
    #pragma unroll
    for (int j = 0; j < 4; ++j){
      unsigned lb = __float_as_uint(la[j]);
      unsigned tv = lb >> 31;
      float    lval = __uint_as_float(lb & 0x7fffffffu);
      unsigned hi = ka[j] >> 16;
      if (hi < pfx16){ sL3 += lval; sT += (int)tv; }
      else if (hi == pfx16){
        unsigned p = atomicAdd(&cnt, 1u);    // LDS atomic, rare (~1/64 px)
        if (p < KC_BUF)
          buf[p] = make_uint4(ka[j], (unsigned)(base + j),
                              __float_as_uint(lval), tv);
      }
    }
  }
  // block-level reduce -> per-block partials (no global atomics)
  #pragma unroll
  for (int o = 32; o; o >>= 1){ sL3 += __shfl_down(sL3, o); sT += __shfl_down(sT, o); }
  if (lane == 0){ wl[wid] = sL3; wt[wid] = sT; }
  __syncthreads();
  if (t == 0){
    partialL3[blk] = wl[0] + wl[1] + wl[2] + wl[3];
    partialT2[blk] = (unsigned)(wt[0] + wt[1] + wt[2] + wt[3]);
    basePos = atomicAdd(&ctrl->candCount[row], cnt);   // ONE global atomic/block
  }
  __syncthreads();
  unsigned n = cnt; if (n > KC_BUF) n = KC_BUF;
  for (unsigned i = t; i < n; i += 256){
    unsigned g = basePos + i;
    if (g < (unsigned)cap) cand[(size_t)row * cap + g] = buf[i];
  }
}

__global__ __launch_bounds__(256) void k_resolve(
    const uint4* __restrict__ cand, int cap, Ctrl* ctrl)
{
  __shared__ unsigned int h[256];
  __shared__ unsigned int selBin, selRem;
  __shared__ float wl[4];
  __shared__ int   wt[4];
  const int t   = threadIdx.x;
  const int row = blockIdx.x;
  unsigned cnt  = ctrl->candCount[row]; if (cnt > (unsigned)cap) cnt = (unsigned)cap;
  unsigned kRem = ctrl->kRem2[row];     if (kRem > cnt) kRem = cnt;
  const uint4* cb = cand + (size_t)row * cap;

  // pass 1: bits [15:8]
  h[t] = 0; __syncthreads();
  for (unsigned i = t; i < cnt; i += 256) atomicAdd(&h[(cb[i].x >> 8) & 255], 1u);
  __syncthreads();
  if (t == 0){
    selBin = 0; selRem = 0;
    unsigned c2 = 0;
    for (int b = 0; b < 256; ++b){
      unsigned nb = c2 + h[b];
      if (c2 < kRem && nb >= kRem){ selBin = (unsigned)b; selRem = kRem - c2; break; }
      c2 = nb;
    }
  }
  __syncthreads();
  unsigned b1 = selBin, kr = selRem;
  __syncthreads();

  // pass 2: bits [7:0] among b1 matches
  h[t] = 0; __syncthreads();
  for (unsigned i = t; i < cnt; i += 256){
    unsigned key = cb[i].x;
    if (((key >> 8) & 255) == b1) atomicAdd(&h[key & 255], 1u);
  }
  __syncthreads();
  if (t == 0){
    selBin = 0; selRem = 0;
    unsigned c2 = 0;
    for (int b = 0; b < 256; ++b){
      unsigned nb = c2 + h[b];
      if (c2 < kr && nb >= kr){ selBin = (unsigned)b; selRem = kr - c2; break; }
      c2 = nb;
    }
  }
  __syncthreads();
  const unsigned T     = (ctrl->prefix16[row] << 16) | (b1 << 8) | selBin;
  const unsigned mNeed = selRem;

  float sL3 = 0.0f; int sT = 0;
  for (unsigned i = t; i < cnt; i += 256){
    uint4 e = cb[i];
    bool take = false;
    if (e.x < T) take = true;
    else if (e.x == T){
      // stable-argsort tie-break: first mNeed by original index
      unsigned rank = 0;
      for (unsigned j2 = 0; j2 < cnt; ++j2){
        uint4 f = cb[j2];
        rank += (f.x == T && f.y < e.y) ? 1u : 0u;
      }
      take = (rank < mNeed);
    }
    if (take){ sL3 += __uint_as_float(e.z); sT += (int)e.w; }
  }
  const int lane = t & 63, wid = t >> 6;
  #pragma unroll
  for (int o = 32; o; o >>= 1){ sL3 += __shfl_down(sL3, o); sT += __shfl_down(sT, o); }
  if (lane == 0){ wl[wid] = sL3; wt[wid] = sT; }
  __syncthreads();
  if (t == 0){
    float a  = wl[0] + wl[1] + wl[2] + wl[3];
    int   b2 = wt[0] + wt[1] + wt[2] + wt[3];
    atomicAdd(&ctrl->selL3, (double)a);                 // 8 blocks total: fine
    atomicAdd(&ctrl->selT, (unsigned long long)(unsigned)b2);
  }
}

__global__ __launch_bounds__(256) void k_final(
    const unsigned int* __restrict__ partialT,
    const float* __restrict__ partialL3,
    const unsigned int* __restrict__ partialT2,
    const Ctrl* __restrict__ ctrl, float* __restrict__ out)
{
  __shared__ double dl[4];
  __shared__ unsigned long long dt[4], dtt[4];
  const int t = threadIdx.x, lane = t & 63, wid = t >> 6;
  unsigned long long tt = 0;
  for (int i = t; i < NROWS * K1_BPR; i += 256) tt += partialT[i];
  double sl = 0.0; unsigned long long st = 0;
  for (int i = t; i < NROWS * KC_BPR; i += 256){
    sl += (double)partialL3[i]; st += partialT2[i];
  }
  #pragma unroll
  for (int o = 32; o; o >>= 1){
    tt += __shfl_down(tt, o); sl += __shfl_down(sl, o); st += __shfl_down(st, o);
  }
  if (lane == 0){ dtt[wid] = tt; dl[wid] = sl; dt[wid] = st; }
  __syncthreads();
  if (t == 0){
    tt = dtt[0] + dtt[1] + dtt[2] + dtt[3];
    sl = dl[0] + dl[1] + dl[2] + dl[3] + ctrl->selL3;
    st = dt[0] + dt[1] + dt[2] + dt[3] + ctrl->selT;
    out[0] = (float)(sl / ((double)NROWS * (double)ctrl->kVal));
    out[1] = (float)((double)st / (double)tt);
  }
}

extern "C" void kernel_launch(void* const* d_in, const int* in_sizes, int n_in,
                              void* d_out, int out_size, void* d_ws, size_t ws_size,
                              hipStream_t stream)
{
  const float* in1  = (const float*)d_in[0];
  const float* in2  = (const float*)d_in[1];
  const float* in3  = (const float*)d_in[2];
  const int*   tgt  = (const int*)d_in[3];
  const float* frp  = (const float*)d_in[4];
  const float* kdwp = (const float*)d_in[5];
  float* out = (float*)d_out;
  char*  ws  = (char*)d_ws;

  const size_t off_keys = 0;
  const size_t off_l3   = (size_t)NROWS * NPIX * 4;              // 8 MB
  const size_t off_h0   = off_l3 + (size_t)NROWS * NPIX * 4;     // 16 MB
  const size_t off_h1   = off_h0 + (size_t)NROWS * 256 * 4;
  const size_t off_ctrl = off_h1 + (size_t)NROWS * 256 * 4;
  const size_t off_pT1  = (off_ctrl + sizeof(Ctrl) + 255) & ~(size_t)255;
  const size_t off_pL3  = off_pT1 + (size_t)NROWS * K1_BPR * 4;
  const size_t off_pT2  = off_pL3 + (size_t)NROWS * KC_BPR * 4;
  const size_t off_cand = (off_pT2 + (size_t)NROWS * KC_BPR * 4 + 255) & ~(size_t)255;

  int cap = CAP;
  if (ws_size < off_cand + (size_t)NROWS * cap * 16){
    size_t avail = (ws_size > off_cand) ? (ws_size - off_cand) / ((size_t)NROWS * 16) : 0;
    cap = (int)avail;
  }

  unsigned int* keys = (unsigned int*)(ws + off_keys);
  float*        l3   = (float*)(ws + off_l3);
  unsigned int* h0   = (unsigned int*)(ws + off_h0);
  unsigned int* h1   = (unsigned int*)(ws + off_h1);
  Ctrl*         ctrl = (Ctrl*)(ws + off_ctrl);
  unsigned int* pT1  = (unsigned int*)(ws + off_pT1);
  float*        pL3  = (float*)(ws + off_pL3);
  unsigned int* pT2  = (unsigned int*)(ws + off_pT2);
  uint4*        cand = (uint4*)(ws + off_cand);

  hipMemsetAsync(ws + off_h0, 0, off_pT1 - off_h0, stream);   // h0,h1,ctrl only
  k_compute<<<NROWS * K1_BPR, 256, 0, stream>>>(in1, in2, in3, tgt, kdwp,
                                                keys, l3, h0, pT1);
  k_scan<<<1, 256, 0, stream>>>(0, h0, ctrl, frp);
  k_refine<<<NROWS * KR_BPR, 256, 0, stream>>>(keys, ctrl, h1);
  k_scan<<<1, 256, 0, stream>>>(1, h1, ctrl, frp);
  k_collect<<<NROWS * KC_BPR, 256, 0, stream>>>(keys, l3, ctrl, cand, cap, pL3, pT2);
  k_resolve<<<NROWS, 256, 0, stream>>>(cand, cap, ctrl);
  k_final<<<1, 256, 0, stream>>>(pT1, pL3, pT2, ctrl, out);
}

// Round 3
// 60.936 us; speedup vs baseline: 5.3735x; 2.3120x over previous
//
#include <hip/hip_runtime.h>

#define NROWS 8
#define NPIX  262144          // 512*512
#define K1_BPR 256            // compute: 1024 px/block, grid 2048
#define KR_BPR 64             // refine : 4096 px/block, grid 512
#define KC_BPR 128            // collect: 2048 px/block, grid 1024
#define KC_BUF 2048           // LDS candidate buffer (= px/block, always safe)
#define CAP    16384          // global candidate buffer capacity per row
#define TIE_CAP 1024

// monotonic float->uint map (ascending float == ascending uint)
__device__ __forceinline__ unsigned int fkey(float x){
  unsigned int u = __float_as_uint(x);
  return (u & 0x80000000u) ? ~u : (u | 0x80000000u);
}

// binary softmax with a single exp
__device__ __forceinline__ void softmax2(float a0, float a1,
    float& lp0, float& lp1, float& p0, float& p1){
  float d  = a1 - a0;
  float ad = -fabsf(d);
  float e  = __expf(ad);
  float s  = 1.0f + e;
  float ls = __logf(s);
  float rs = __builtin_amdgcn_rcpf(s);
  float lpM = -ls,  lpm = ad - ls;
  float pM  = rs,   pm  = e * rs;
  bool g = (d >= 0.0f);
  lp1 = g ? lpM : lpm;  lp0 = g ? lpm : lpM;
  p1  = g ? pM  : pm;   p0  = g ? pm  : pM;
}

__device__ __forceinline__ float focal2(float tt, float lp0, float lp1,
                                        float p0, float p1){
  float q1 = 1.0f - p1, q0 = 1.0f - p0;
  return -(tt * q1 * q1 * lp1) - ((1.0f - tt) * q0 * q0 * lp0);
}

// parallel 256-bin select: returns (bin, kRem-within-bin). Requires 256 threads.
// cum/res are LDS scratch. Fully barriered; safe to call repeatedly.
__device__ __forceinline__ uint2 selectBinV(unsigned v, unsigned kRem,
    unsigned* cum, unsigned* res){
  const int t = threadIdx.x;
  cum[t] = v;
  if (t == 0){ res[0] = 255u; res[1] = kRem; }
  __syncthreads();
  unsigned run = v;
  #pragma unroll
  for (int off = 1; off < 256; off <<= 1){
    unsigned add = (t >= off) ? cum[t - off] : 0u;
    __syncthreads();
    run += add;
    cum[t] = run;
    __syncthreads();
  }
  unsigned inc = cum[t], exc = inc - v;
  if (exc < kRem && inc >= kRem) { res[0] = (unsigned)t; res[1] = kRem - exc; }
  __syncthreads();
  uint2 r = make_uint2(res[0], res[1]);
  __syncthreads();
  return r;
}

__device__ __forceinline__ unsigned kTop(const float* frp){
  return (unsigned)((1.0 - (double)(*frp)) * (double)NPIX);   // 209715
}

__global__ __launch_bounds__(256) void k_compute(
    const float* __restrict__ in1, const float* __restrict__ in2,
    const float* __restrict__ in3, const int* __restrict__ tgt,
    const float* __restrict__ kdwp,
    unsigned int* __restrict__ keys, float* __restrict__ l3out,
    unsigned int* __restrict__ hist0, unsigned int* __restrict__ partialT)
{
  __shared__ unsigned int h[256];
  __shared__ int wt[4];
  const int t = threadIdx.x;
  h[t] = 0;
  __syncthreads();

  const int blk   = blockIdx.x;
  const int row   = blk / K1_BPR;
  const int chunk = (blk % K1_BPR) * (NPIX / K1_BPR);
  const int base  = chunk + 4 * t;
  const float kdw = *kdwp;
  const float w1  = (float)(1.0 - (double)kdw);

  const size_t ro2 = (size_t)row * 2 * NPIX;
  const size_t ro1 = (size_t)row * NPIX;

  float4 x10 = *(const float4*)(in1 + ro2 + base);
  float4 x11 = *(const float4*)(in1 + ro2 + NPIX + base);
  float4 x20 = *(const float4*)(in2 + ro2 + base);
  float4 x21 = *(const float4*)(in2 + ro2 + NPIX + base);
  float4 x30 = *(const float4*)(in3 + ro2 + base);
  float4 x31 = *(const float4*)(in3 + ro2 + NPIX + base);
  int4   tg  = *(const int4*)(tgt + ro1 + base);

  float a10[4] = {x10.x, x10.y, x10.z, x10.w};
  float a11[4] = {x11.x, x11.y, x11.z, x11.w};
  float a20[4] = {x20.x, x20.y, x20.z, x20.w};
  float a21[4] = {x21.x, x21.y, x21.z, x21.w};
  float a30[4] = {x30.x, x30.y, x30.z, x30.w};
  float a31[4] = {x31.x, x31.y, x31.z, x31.w};
  int   tgv[4] = {tg.x, tg.y, tg.z, tg.w};

  unsigned int kv[4]; float l3v[4];
  int myT = 0;
  #pragma unroll
  for (int j = 0; j < 4; ++j){
    float tt = (float)tgv[j]; myT += tgv[j];
    float lp10, lp11, p10, p11; softmax2(a10[j], a11[j], lp10, lp11, p10, p11);
    float lp20, lp21, p20, p21; softmax2(a20[j], a21[j], lp20, lp21, p20, p21);
    float lp30, lp31, p30, p31; softmax2(a30[j], a31[j], lp30, lp31, p30, p31);
    float l1 = focal2(tt, lp10, lp11, p10, p11);
    float l2 = focal2(tt, lp20, lp21, p20, p21);
    float l3 = focal2(tt, lp30, lp31, p30, p31);
    float kdl12 = p10 * (lp10 - lp20) + p11 * (lp11 - lp21);
    float kdl21 = p20 * (lp20 - lp10) + p21 * (lp21 - lp11);
    float loss  = w1 * (l1 + l2 + l3) + kdw * (kdl12 + kdl21);
    kv[j]  = fkey(loss);
    // pack target into sign bit (focal loss >= 0): collect needn't re-read tgt
    l3v[j] = __uint_as_float(__float_as_uint(l3) | ((unsigned)tgv[j] << 31));
  }
  *(uint4*)(keys + ro1 + base)   = make_uint4(kv[0], kv[1], kv[2], kv[3]);
  *(float4*)(l3out + ro1 + base) = make_float4(l3v[0], l3v[1], l3v[2], l3v[3]);

  // wave-aggregated LDS histogram of key[31:24] (exponent bits concentrate)
  const int lane = t & 63;
  #pragma unroll
  for (int j = 0; j < 4; ++j){
    unsigned bin = kv[j] >> 24;
    unsigned long long rem = ~0ull;
    while (rem){
      int lead = __ffsll(rem) - 1;
      unsigned leadBin = (unsigned)__shfl((int)bin, lead);
      unsigned long long same = __ballot(bin == leadBin);
      if (lane == lead) atomicAdd(&h[leadBin], (unsigned)__popcll(same));
      rem &= ~same;
    }
  }

  int wsum = myT;
  #pragma unroll
  for (int o = 32; o; o >>= 1) wsum += __shfl_down(wsum, o);
  if (lane == 0) wt[t >> 6] = wsum;

  __syncthreads();
  unsigned hv = h[t];
  if (hv) atomicAdd(&hist0[row * 256 + t], hv);
  if (t == 0) partialT[blk] = (unsigned)(wt[0] + wt[1] + wt[2] + wt[3]);
}

__global__ __launch_bounds__(256) void k_refine(
    const unsigned int* __restrict__ keys,
    const unsigned int* __restrict__ hist0,
    const float* __restrict__ frp,
    unsigned int* __restrict__ hist1)
{
  __shared__ unsigned cum[256];
  __shared__ unsigned res[2];
  __shared__ unsigned h[256];
  const int t = threadIdx.x;
  const int row   = blockIdx.x / KR_BPR;
  const int chunk = (blockIdx.x % KR_BPR) * (NPIX / KR_BPR);

  uint2 s0 = selectBinV(hist0[row * 256 + t], kTop(frp), cum, res);
  const unsigned pfx = s0.x;

  h[t] = 0;
  __syncthreads();
  const uint4* kp = (const uint4*)(keys + (size_t)row * NPIX + chunk);
  #pragma unroll
  for (int it = 0; it < 4; ++it){
    uint4 kvv = kp[it * 256 + t];
    unsigned a[4] = {kvv.x, kvv.y, kvv.z, kvv.w};
    #pragma unroll
    for (int j = 0; j < 4; ++j)
      if ((a[j] >> 24) == pfx) atomicAdd(&h[(a[j] >> 16) & 255], 1u);
  }
  __syncthreads();
  unsigned hv = h[t];
  if (hv) atomicAdd(&hist1[row * 256 + t], hv);
}

__global__ __launch_bounds__(256) void k_collect(
    const unsigned int* __restrict__ keys, const float* __restrict__ l3,
    const unsigned int* __restrict__ hist0,
    const unsigned int* __restrict__ hist1,
    const float* __restrict__ frp,
    unsigned int* __restrict__ candCount, uint4* __restrict__ cand, int cap,
    float* __restrict__ partialL3, unsigned int* __restrict__ partialT2)
{
  __shared__ uint4 buf[KC_BUF];            // 32 KB candidate staging
  __shared__ unsigned cum[256];
  __shared__ unsigned res[2];
  __shared__ unsigned cnt, basePos;
  __shared__ float wl[4];
  __shared__ int   wt[4];
  const int t    = threadIdx.x;
  const int lane = t & 63, wid = t >> 6;
  const int blk   = blockIdx.x;
  const int row   = blk / KC_BPR;
  const int chunk = (blk % KC_BPR) * (NPIX / KC_BPR);
  const size_t ro = (size_t)row * NPIX;

  if (t == 0) cnt = 0;
  uint2 s0 = selectBinV(hist0[row * 256 + t], kTop(frp), cum, res);
  uint2 s1 = selectBinV(hist1[row * 256 + t], s0.y, cum, res);
  const unsigned pfx16 = (s0.x << 8) | s1.x;

  float sL3 = 0.0f; int sT = 0;
  #pragma unroll
  for (int it = 0; it < 2; ++it){
    int base = chunk + it * 1024 + 4 * t;
    uint4  kvv = *(const uint4*)(keys + ro + base);
    float4 lv  = *(const float4*)(l3  + ro + base);
    unsigned ka[4] = {kvv.x, kvv.y, kvv.z, kvv.w};
    float    la[4] = {lv.x, lv.y, lv.z, lv.w};
    #pragma unroll
    for (int j = 0; j < 4; ++j){
      unsigned lb = __float_as_uint(la[j]);
      unsigned tv = lb >> 31;
      float    lval = __uint_as_float(lb & 0x7fffffffu);
      unsigned hi = ka[j] >> 16;
      if (hi < pfx16){ sL3 += lval; sT += (int)tv; }
      else if (hi == pfx16){
        unsigned p = atomicAdd(&cnt, 1u);    // LDS atomic, rare
        if (p < KC_BUF)
          buf[p] = make_uint4(ka[j], (unsigned)(base + j),
                              __float_as_uint(lval), tv);
      }
    }
  }
  #pragma unroll
  for (int o = 32; o; o >>= 1){ sL3 += __shfl_down(sL3, o); sT += __shfl_down(sT, o); }
  if (lane == 0){ wl[wid] = sL3; wt[wid] = sT; }
  __syncthreads();
  if (t == 0){
    partialL3[blk] = wl[0] + wl[1] + wl[2] + wl[3];
    partialT2[blk] = (unsigned)(wt[0] + wt[1] + wt[2] + wt[3]);
    basePos = atomicAdd(&candCount[row], cnt);   // ONE global atomic/block
  }
  __syncthreads();
  unsigned n = cnt; if (n > KC_BUF) n = KC_BUF;
  for (unsigned i = t; i < n; i += 256){
    unsigned g = basePos + i;
    if (g < (unsigned)cap) cand[(size_t)row * cap + g] = buf[i];
  }
}

__global__ __launch_bounds__(256) void k_resolve(
    const unsigned int* __restrict__ hist0,
    const unsigned int* __restrict__ hist1,
    const float* __restrict__ frp,
    const unsigned int* __restrict__ candCount,
    const uint4* __restrict__ cand, int cap,
    float* __restrict__ rowL3, unsigned int* __restrict__ rowT)
{
  __shared__ unsigned cum[256];
  __shared__ unsigned res[2];
  __shared__ unsigned h[256];
  __shared__ uint4 ties[TIE_CAP];
  __shared__ unsigned tieN;
  __shared__ float wl[4];
  __shared__ int   wt[4];
  const int t   = threadIdx.x;
  const int row = blockIdx.x;

  if (t == 0) tieN = 0;
  uint2 s0 = selectBinV(hist0[row * 256 + t], kTop(frp), cum, res);
  uint2 s1 = selectBinV(hist1[row * 256 + t], s0.y, cum, res);
  const unsigned pfx16 = (s0.x << 8) | s1.x;

  unsigned cnt  = candCount[row]; if (cnt > (unsigned)cap) cnt = (unsigned)cap;
  unsigned kRem = s1.y;           if (kRem > cnt) kRem = cnt;
  const uint4* cb = cand + (size_t)row * cap;

  // pass 1: bits [15:8]  (parallel histogram + parallel scan select)
  h[t] = 0; __syncthreads();
  for (unsigned i = t; i < cnt; i += 256) atomicAdd(&h[(cb[i].x >> 8) & 255], 1u);
  __syncthreads();
  uint2 s2 = selectBinV(h[t], kRem, cum, res);
  const unsigned b1 = s2.x;

  // pass 2: bits [7:0] among b1 matches
  h[t] = 0; __syncthreads();
  for (unsigned i = t; i < cnt; i += 256){
    unsigned key = cb[i].x;
    if (((key >> 8) & 255) == b1) atomicAdd(&h[key & 255], 1u);
  }
  __syncthreads();
  uint2 s3 = selectBinV(h[t], s2.y, cum, res);

  const unsigned T     = (pfx16 << 16) | (b1 << 8) | s3.x;
  const unsigned mNeed = s3.y;

  float sL3 = 0.0f; int sT = 0;
  for (unsigned i = t; i < cnt; i += 256){
    uint4 e = cb[i];
    if (e.x < T){ sL3 += __uint_as_float(e.z); sT += (int)e.w; }
    else if (e.x == T){
      unsigned p = atomicAdd(&tieN, 1u);
      if (p < TIE_CAP) ties[p] = e;
    }
  }
  __syncthreads();
  // stable tie-break among key==T: take mNeed smallest original indices
  unsigned tn = tieN; if (tn > TIE_CAP) tn = TIE_CAP;
  if ((unsigned)t < tn){
    uint4 e = ties[t];
    unsigned rank = 0;
    for (unsigned j = 0; j < tn; ++j) rank += (ties[j].y < e.y) ? 1u : 0u;
    if (rank < mNeed){ sL3 += __uint_as_float(e.z); sT += (int)e.w; }
  }
  const int lane = t & 63, wid = t >> 6;
  #pragma unroll
  for (int o = 32; o; o >>= 1){ sL3 += __shfl_down(sL3, o); sT += __shfl_down(sT, o); }
  if (lane == 0){ wl[wid] = sL3; wt[wid] = sT; }
  __syncthreads();
  if (t == 0){
    rowL3[row] = wl[0] + wl[1] + wl[2] + wl[3];
    rowT[row]  = (unsigned)(wt[0] + wt[1] + wt[2] + wt[3]);
  }
}

__global__ __launch_bounds__(256) void k_final(
    const unsigned int* __restrict__ partialT,
    const float* __restrict__ partialL3,
    const unsigned int* __restrict__ partialT2,
    const float* __restrict__ rowL3, const unsigned int* __restrict__ rowT,
    const float* __restrict__ frp, float* __restrict__ out)
{
  __shared__ double dl[4];
  __shared__ unsigned long long dt[4], dtt[4];
  const int t = threadIdx.x, lane = t & 63, wid = t >> 6;
  unsigned long long tt = 0;
  for (int i = t; i < NROWS * K1_BPR; i += 256) tt += partialT[i];
  double sl = 0.0; unsigned long long st = 0;
  for (int i = t; i < NROWS * KC_BPR; i += 256){
    sl += (double)partialL3[i]; st += partialT2[i];
  }
  if (t < NROWS){ sl += (double)rowL3[t]; st += rowT[t]; }
  #pragma unroll
  for (int o = 32; o; o >>= 1){
    tt += __shfl_down(tt, o); sl += __shfl_down(sl, o); st += __shfl_down(st, o);
  }
  if (lane == 0){ dtt[wid] = tt; dl[wid] = sl; dt[wid] = st; }
  __syncthreads();
  if (t == 0){
    tt = dtt[0] + dtt[1] + dtt[2] + dtt[3];
    sl = dl[0] + dl[1] + dl[2] + dl[3];
    st = dt[0] + dt[1] + dt[2] + dt[3];
    out[0] = (float)(sl / ((double)NROWS * (double)kTop(frp)));
    out[1] = (float)((double)st / (double)tt);
  }
}

extern "C" void kernel_launch(void* const* d_in, const int* in_sizes, int n_in,
                              void* d_out, int out_size, void* d_ws, size_t ws_size,
                              hipStream_t stream)
{
  const float* in1  = (const float*)d_in[0];
  const float* in2  = (const float*)d_in[1];
  const float* in3  = (const float*)d_in[2];
  const int*   tgt  = (const int*)d_in[3];
  const float* frp  = (const float*)d_in[4];
  const float* kdwp = (const float*)d_in[5];
  float* out = (float*)d_out;
  char*  ws  = (char*)d_ws;

  const size_t off_keys = 0;
  const size_t off_l3   = (size_t)NROWS * NPIX * 4;              // 8 MB
  const size_t off_h0   = off_l3 + (size_t)NROWS * NPIX * 4;     // 16 MB
  const size_t off_h1   = off_h0 + (size_t)NROWS * 256 * 4;
  const size_t off_cc   = off_h1 + (size_t)NROWS * 256 * 4;      // candCount
  const size_t zero_end = off_cc + (size_t)NROWS * 4;
  const size_t off_pT1  = (zero_end + 255) & ~(size_t)255;
  const size_t off_pL3  = off_pT1 + (size_t)NROWS * K1_BPR * 4;
  const size_t off_pT2  = off_pL3 + (size_t)NROWS * KC_BPR * 4;
  const size_t off_rL3  = off_pT2 + (size_t)NROWS * KC_BPR * 4;
  const size_t off_rT   = off_rL3 + (size_t)NROWS * 4;
  const size_t off_cand = (off_rT + (size_t)NROWS * 4 + 255) & ~(size_t)255;

  int cap = CAP;
  if (ws_size < off_cand + (size_t)NROWS * cap * 16){
    size_t avail = (ws_size > off_cand) ? (ws_size - off_cand) / ((size_t)NROWS * 16) : 0;
    cap = (int)avail;
  }

  unsigned int* keys = (unsigned int*)(ws + off_keys);
  float*        l3   = (float*)(ws + off_l3);
  unsigned int* h0   = (unsigned int*)(ws + off_h0);
  unsigned int* h1   = (unsigned int*)(ws + off_h1);
  unsigned int* cc   = (unsigned int*)(ws + off_cc);
  unsigned int* pT1  = (unsigned int*)(ws + off_pT1);
  float*        pL3  = (float*)(ws + off_pL3);
  unsigned int* pT2  = (unsigned int*)(ws + off_pT2);
  float*        rL3  = (float*)(ws + off_rL3);
  unsigned int* rT   = (unsigned int*)(ws + off_rT);
  uint4*        cand = (uint4*)(ws + off_cand);

  hipMemsetAsync(ws + off_h0, 0, zero_end - off_h0, stream);   // h0,h1,candCount
  k_compute<<<NROWS * K1_BPR, 256, 0, stream>>>(in1, in2, in3, tgt, kdwp,
                                                keys, l3, h0, pT1);
  k_refine<<<NROWS * KR_BPR, 256, 0, stream>>>(keys, h0, frp, h1);
  k_collect<<<NROWS * KC_BPR, 256, 0, stream>>>(keys, l3, h0, h1, frp,
                                                cc, cand, cap, pL3, pT2);
  k_resolve<<<NROWS, 256, 0, stream>>>(h0, h1, frp, cc, cand, cap, rL3, rT);
  k_final<<<1, 256, 0, stream>>>(pT1, pL3, pT2, rL3, rT, frp, out);
}

// Round 4
// 60.927 us; speedup vs baseline: 5.3743x; 1.0001x over previous
//
#include <hip/hip_runtime.h>

#define NROWS 8
#define NPIX  262144          // 512*512
#define K1_BPR 256            // compute: 1024 px/block, grid 2048
#define KR_BPR 64             // refine : 4096 px/block, grid 512
#define KC_BPR 128            // collect: 2048 px/block, grid 1024
#define KC_BUF 2048           // LDS candidate buffer (= px/block, always safe)
#define CAP    16384          // global candidate buffer capacity per row
#define TIE_CAP 1024

// monotonic float->uint map (ascending float == ascending uint)
__device__ __forceinline__ unsigned int fkey(float x){
  unsigned int u = __float_as_uint(x);
  return (u & 0x80000000u) ? ~u : (u | 0x80000000u);
}

// binary softmax with a single exp
__device__ __forceinline__ void softmax2(float a0, float a1,
    float& lp0, float& lp1, float& p0, float& p1){
  float d  = a1 - a0;
  float ad = -fabsf(d);
  float e  = __expf(ad);
  float s  = 1.0f + e;
  float ls = __logf(s);
  float rs = __builtin_amdgcn_rcpf(s);
  float lpM = -ls,  lpm = ad - ls;
  float pM  = rs,   pm  = e * rs;
  bool g = (d >= 0.0f);
  lp1 = g ? lpM : lpm;  lp0 = g ? lpm : lpM;
  p1  = g ? pM  : pm;   p0  = g ? pm  : pM;
}

__device__ __forceinline__ float focal2(float tt, float lp0, float lp1,
                                        float p0, float p1){
  float q1 = 1.0f - p1, q0 = 1.0f - p0;
  return -(tt * q1 * q1 * lp1) - ((1.0f - tt) * q0 * q0 * lp0);
}

// parallel 256-bin select: returns (bin, kRem-within-bin). Requires 256 threads.
__device__ __forceinline__ uint2 selectBinV(unsigned v, unsigned kRem,
    unsigned* cum, unsigned* res){
  const int t = threadIdx.x;
  cum[t] = v;
  if (t == 0){ res[0] = 255u; res[1] = kRem; }
  __syncthreads();
  unsigned run = v;
  #pragma unroll
  for (int off = 1; off < 256; off <<= 1){
    unsigned add = (t >= off) ? cum[t - off] : 0u;
    __syncthreads();
    run += add;
    cum[t] = run;
    __syncthreads();
  }
  unsigned inc = cum[t], exc = inc - v;
  if (exc < kRem && inc >= kRem) { res[0] = (unsigned)t; res[1] = kRem - exc; }
  __syncthreads();
  uint2 r = make_uint2(res[0], res[1]);
  __syncthreads();
  return r;
}

__device__ __forceinline__ unsigned kTop(const float* frp){
  return (unsigned)((1.0 - (double)(*frp)) * (double)NPIX);   // 209715
}

// tiny zero kernel: the runtime's fillBuffer for small sizes cost ~39 us(!)
__global__ __launch_bounds__(256) void k_zero(unsigned int* __restrict__ p, int n){
  int i = blockIdx.x * 256 + threadIdx.x;
  int stride = gridDim.x * 256;
  for (; i < n; i += stride) p[i] = 0u;
}

__global__ __launch_bounds__(256) void k_compute(
    const float* __restrict__ in1, const float* __restrict__ in2,
    const float* __restrict__ in3, const int* __restrict__ tgt,
    const float* __restrict__ kdwp,
    unsigned int* __restrict__ keys, float* __restrict__ l3out,
    unsigned int* __restrict__ hist0, unsigned int* __restrict__ partialT)
{
  __shared__ unsigned int h[256];
  __shared__ int wt[4];
  const int t = threadIdx.x;
  h[t] = 0;
  __syncthreads();

  const int blk   = blockIdx.x;
  const int row   = blk / K1_BPR;
  const int chunk = (blk % K1_BPR) * (NPIX / K1_BPR);
  const int base  = chunk + 4 * t;
  const float kdw = *kdwp;
  const float w1  = (float)(1.0 - (double)kdw);

  const size_t ro2 = (size_t)row * 2 * NPIX;
  const size_t ro1 = (size_t)row * NPIX;

  float4 x10 = *(const float4*)(in1 + ro2 + base);
  float4 x11 = *(const float4*)(in1 + ro2 + NPIX + base);
  float4 x20 = *(const float4*)(in2 + ro2 + base);
  float4 x21 = *(const float4*)(in2 + ro2 + NPIX + base);
  float4 x30 = *(const float4*)(in3 + ro2 + base);
  float4 x31 = *(const float4*)(in3 + ro2 + NPIX + base);
  int4   tg  = *(const int4*)(tgt + ro1 + base);

  float a10[4] = {x10.x, x10.y, x10.z, x10.w};
  float a11[4] = {x11.x, x11.y, x11.z, x11.w};
  float a20[4] = {x20.x, x20.y, x20.z, x20.w};
  float a21[4] = {x21.x, x21.y, x21.z, x21.w};
  float a30[4] = {x30.x, x30.y, x30.z, x30.w};
  float a31[4] = {x31.x, x31.y, x31.z, x31.w};
  int   tgv[4] = {tg.x, tg.y, tg.z, tg.w};

  unsigned int kv[4]; float l3v[4];
  int myT = 0;
  #pragma unroll
  for (int j = 0; j < 4; ++j){
    float tt = (float)tgv[j]; myT += tgv[j];
    float lp10, lp11, p10, p11; softmax2(a10[j], a11[j], lp10, lp11, p10, p11);
    float lp20, lp21, p20, p21; softmax2(a20[j], a21[j], lp20, lp21, p20, p21);
    float lp30, lp31, p30, p31; softmax2(a30[j], a31[j], lp30, lp31, p30, p31);
    float l1 = focal2(tt, lp10, lp11, p10, p11);
    float l2 = focal2(tt, lp20, lp21, p20, p21);
    float l3 = focal2(tt, lp30, lp31, p30, p31);
    float kdl12 = p10 * (lp10 - lp20) + p11 * (lp11 - lp21);
    float kdl21 = p20 * (lp20 - lp10) + p21 * (lp21 - lp11);
    float loss  = w1 * (l1 + l2 + l3) + kdw * (kdl12 + kdl21);
    kv[j]  = fkey(loss);
    // pack target into sign bit (focal loss >= 0): collect needn't re-read tgt
    l3v[j] = __uint_as_float(__float_as_uint(l3) | ((unsigned)tgv[j] << 31));
  }
  *(uint4*)(keys + ro1 + base)   = make_uint4(kv[0], kv[1], kv[2], kv[3]);
  *(float4*)(l3out + ro1 + base) = make_float4(l3v[0], l3v[1], l3v[2], l3v[3]);

  // wave-aggregated LDS histogram of key[31:24] (exponent bits concentrate)
  const int lane = t & 63;
  #pragma unroll
  for (int j = 0; j < 4; ++j){
    unsigned bin = kv[j] >> 24;
    unsigned long long rem = ~0ull;
    while (rem){
      int lead = __ffsll(rem) - 1;
      unsigned leadBin = (unsigned)__shfl((int)bin, lead);
      unsigned long long same = __ballot(bin == leadBin);
      if (lane == lead) atomicAdd(&h[leadBin], (unsigned)__popcll(same));
      rem &= ~same;
    }
  }

  int wsum = myT;
  #pragma unroll
  for (int o = 32; o; o >>= 1) wsum += __shfl_down(wsum, o);
  if (lane == 0) wt[t >> 6] = wsum;

  __syncthreads();
  unsigned hv = h[t];
  if (hv) atomicAdd(&hist0[row * 256 + t], hv);
  if (t == 0) partialT[blk] = (unsigned)(wt[0] + wt[1] + wt[2] + wt[3]);
}

__global__ __launch_bounds__(256) void k_refine(
    const unsigned int* __restrict__ keys,
    const unsigned int* __restrict__ hist0,
    const float* __restrict__ frp,
    unsigned int* __restrict__ hist1)
{
  __shared__ unsigned cum[256];
  __shared__ unsigned res[2];
  __shared__ unsigned h[256];
  const int t = threadIdx.x;
  const int row   = blockIdx.x / KR_BPR;
  const int chunk = (blockIdx.x % KR_BPR) * (NPIX / KR_BPR);

  uint2 s0 = selectBinV(hist0[row * 256 + t], kTop(frp), cum, res);
  const unsigned pfx = s0.x;

  h[t] = 0;
  __syncthreads();
  const uint4* kp = (const uint4*)(keys + (size_t)row * NPIX + chunk);
  #pragma unroll
  for (int it = 0; it < 4; ++it){
    uint4 kvv = kp[it * 256 + t];
    unsigned a[4] = {kvv.x, kvv.y, kvv.z, kvv.w};
    #pragma unroll
    for (int j = 0; j < 4; ++j)
      if ((a[j] >> 24) == pfx) atomicAdd(&h[(a[j] >> 16) & 255], 1u);
  }
  __syncthreads();
  unsigned hv = h[t];
  if (hv) atomicAdd(&hist1[row * 256 + t], hv);
}

__global__ __launch_bounds__(256) void k_collect(
    const unsigned int* __restrict__ keys, const float* __restrict__ l3,
    const unsigned int* __restrict__ hist0,
    const unsigned int* __restrict__ hist1,
    const float* __restrict__ frp,
    unsigned int* __restrict__ candCount, uint4* __restrict__ cand, int cap,
    float* __restrict__ partialL3, unsigned int* __restrict__ partialT2)
{
  __shared__ uint4 buf[KC_BUF];            // 32 KB candidate staging
  __shared__ unsigned cum[256];
  __shared__ unsigned res[2];
  __shared__ unsigned cnt, basePos;
  __shared__ float wl[4];
  __shared__ int   wt[4];
  const int t    = threadIdx.x;
  const int lane = t & 63, wid = t >> 6;
  const int blk   = blockIdx.x;
  const int row   = blk / KC_BPR;
  const int chunk = (blk % KC_BPR) * (NPIX / KC_BPR);
  const size_t ro = (size_t)row * NPIX;

  if (t == 0) cnt = 0;
  uint2 s0 = selectBinV(hist0[row * 256 + t], kTop(frp), cum, res);
  uint2 s1 = selectBinV(hist1[row * 256 + t], s0.y, cum, res);
  const unsigned pfx16 = (s0.x << 8) | s1.x;

  float sL3 = 0.0f; int sT = 0;
  #pragma unroll
  for (int it = 0; it < 2; ++it){
    int base = chunk + it * 1024 + 4 * t;
    uint4  kvv = *(const uint4*)(keys + ro + base);
    float4 lv  = *(const float4*)(l3  + ro + base);
    unsigned ka[4] = {kvv.x, kvv.y, kvv.z, kvv.w};
    float    la[4] = {lv.x, lv.y, lv.z, lv.w};
    #pragma unroll
    for (int j = 0; j < 4; ++j){
      unsigned lb = __float_as_uint(la[j]);
      unsigned tv = lb >> 31;
      float    lval = __uint_as_float(lb & 0x7fffffffu);
      unsigned hi = ka[j] >> 16;
      if (hi < pfx16){ sL3 += lval; sT += (int)tv; }
      else if (hi == pfx16){
        unsigned p = atomicAdd(&cnt, 1u);    // LDS atomic, rare
        if (p < KC_BUF)
          buf[p] = make_uint4(ka[j], (unsigned)(base + j),
                              __float_as_uint(lval), tv);
      }
    }
  }
  #pragma unroll
  for (int o = 32; o; o >>= 1){ sL3 += __shfl_down(sL3, o); sT += __shfl_down(sT, o); }
  if (lane == 0){ wl[wid] = sL3; wt[wid] = sT; }
  __syncthreads();
  if (t == 0){
    partialL3[blk] = wl[0] + wl[1] + wl[2] + wl[3];
    partialT2[blk] = (unsigned)(wt[0] + wt[1] + wt[2] + wt[3]);
    basePos = atomicAdd(&candCount[row], cnt);   // ONE global atomic/block
  }
  __syncthreads();
  unsigned n = cnt; if (n > KC_BUF) n = KC_BUF;
  for (unsigned i = t; i < n; i += 256){
    unsigned g = basePos + i;
    if (g < (unsigned)cap) cand[(size_t)row * cap + g] = buf[i];
  }
}

__global__ __launch_bounds__(256) void k_resolve(
    const unsigned int* __restrict__ hist0,
    const unsigned int* __restrict__ hist1,
    const float* __restrict__ frp,
    const unsigned int* __restrict__ candCount,
    const uint4* __restrict__ cand, int cap,
    float* __restrict__ rowL3, unsigned int* __restrict__ rowT)
{
  __shared__ unsigned cum[256];
  __shared__ unsigned res[2];
  __shared__ unsigned h[256];
  __shared__ uint4 ties[TIE_CAP];
  __shared__ unsigned tieN;
  __shared__ float wl[4];
  __shared__ int   wt[4];
  const int t   = threadIdx.x;
  const int row = blockIdx.x;

  if (t == 0) tieN = 0;
  uint2 s0 = selectBinV(hist0[row * 256 + t], kTop(frp), cum, res);
  uint2 s1 = selectBinV(hist1[row * 256 + t], s0.y, cum, res);
  const unsigned pfx16 = (s0.x << 8) | s1.x;

  unsigned cnt  = candCount[row]; if (cnt > (unsigned)cap) cnt = (unsigned)cap;
  unsigned kRem = s1.y;           if (kRem > cnt) kRem = cnt;
  const uint4* cb = cand + (size_t)row * cap;

  // pass 1: bits [15:8]
  h[t] = 0; __syncthreads();
  for (unsigned i = t; i < cnt; i += 256) atomicAdd(&h[(cb[i].x >> 8) & 255], 1u);
  __syncthreads();
  uint2 s2 = selectBinV(h[t], kRem, cum, res);
  const unsigned b1 = s2.x;

  // pass 2: bits [7:0] among b1 matches
  h[t] = 0; __syncthreads();
  for (unsigned i = t; i < cnt; i += 256){
    unsigned key = cb[i].x;
    if (((key >> 8) & 255) == b1) atomicAdd(&h[key & 255], 1u);
  }
  __syncthreads();
  uint2 s3 = selectBinV(h[t], s2.y, cum, res);

  const unsigned T     = (pfx16 << 16) | (b1 << 8) | s3.x;
  const unsigned mNeed = s3.y;

  float sL3 = 0.0f; int sT = 0;
  for (unsigned i = t; i < cnt; i += 256){
    uint4 e = cb[i];
    if (e.x < T){ sL3 += __uint_as_float(e.z); sT += (int)e.w; }
    else if (e.x == T){
      unsigned p = atomicAdd(&tieN, 1u);
      if (p < TIE_CAP) ties[p] = e;
    }
  }
  __syncthreads();
  // stable tie-break among key==T: take mNeed smallest original indices
  unsigned tn = tieN; if (tn > TIE_CAP) tn = TIE_CAP;
  if ((unsigned)t < tn){
    uint4 e = ties[t];
    unsigned rank = 0;
    for (unsigned j = 0; j < tn; ++j) rank += (ties[j].y < e.y) ? 1u : 0u;
    if (rank < mNeed){ sL3 += __uint_as_float(e.z); sT += (int)e.w; }
  }
  const int lane = t & 63, wid = t >> 6;
  #pragma unroll
  for (int o = 32; o; o >>= 1){ sL3 += __shfl_down(sL3, o); sT += __shfl_down(sT, o); }
  if (lane == 0){ wl[wid] = sL3; wt[wid] = sT; }
  __syncthreads();
  if (t == 0){
    rowL3[row] = wl[0] + wl[1] + wl[2] + wl[3];
    rowT[row]  = (unsigned)(wt[0] + wt[1] + wt[2] + wt[3]);
  }
}

__global__ __launch_bounds__(256) void k_final(
    const unsigned int* __restrict__ partialT,
    const float* __restrict__ partialL3,
    const unsigned int* __restrict__ partialT2,
    const float* __restrict__ rowL3, const unsigned int* __restrict__ rowT,
    const float* __restrict__ frp, float* __restrict__ out)
{
  __shared__ double dl[4];
  __shared__ unsigned long long dt[4], dtt[4];
  const int t = threadIdx.x, lane = t & 63, wid = t >> 6;
  unsigned long long tt = 0;
  for (int i = t; i < NROWS * K1_BPR; i += 256) tt += partialT[i];
  double sl = 0.0; unsigned long long st = 0;
  for (int i = t; i < NROWS * KC_BPR; i += 256){
    sl += (double)partialL3[i]; st += partialT2[i];
  }
  if (t < NROWS){ sl += (double)rowL3[t]; st += rowT[t]; }
  #pragma unroll
  for (int o = 32; o; o >>= 1){
    tt += __shfl_down(tt, o); sl += __shfl_down(sl, o); st += __shfl_down(st, o);
  }
  if (lane == 0){ dtt[wid] = tt; dl[wid] = sl; dt[wid] = st; }
  __syncthreads();
  if (t == 0){
    tt = dtt[0] + dtt[1] + dtt[2] + dtt[3];
    sl = dl[0] + dl[1] + dl[2] + dl[3];
    st = dt[0] + dt[1] + dt[2] + dt[3];
    out[0] = (float)(sl / ((double)NROWS * (double)kTop(frp)));
    out[1] = (float)((double)st / (double)tt);
  }
}

extern "C" void kernel_launch(void* const* d_in, const int* in_sizes, int n_in,
                              void* d_out, int out_size, void* d_ws, size_t ws_size,
                              hipStream_t stream)
{
  const float* in1  = (const float*)d_in[0];
  const float* in2  = (const float*)d_in[1];
  const float* in3  = (const float*)d_in[2];
  const int*   tgt  = (const int*)d_in[3];
  const float* frp  = (const float*)d_in[4];
  const float* kdwp = (const float*)d_in[5];
  float* out = (float*)d_out;
  char*  ws  = (char*)d_ws;

  const size_t off_keys = 0;
  const size_t off_l3   = (size_t)NROWS * NPIX * 4;              // 8 MB
  const size_t off_h0   = off_l3 + (size_t)NROWS * NPIX * 4;     // 16 MB
  const size_t off_h1   = off_h0 + (size_t)NROWS * 256 * 4;
  const size_t off_cc   = off_h1 + (size_t)NROWS * 256 * 4;      // candCount
  const size_t zero_end = off_cc + (size_t)NROWS * 4;
  const size_t off_pT1  = (zero_end + 255) & ~(size_t)255;
  const size_t off_pL3  = off_pT1 + (size_t)NROWS * K1_BPR * 4;
  const size_t off_pT2  = off_pL3 + (size_t)NROWS * KC_BPR * 4;
  const size_t off_rL3  = off_pT2 + (size_t)NROWS * KC_BPR * 4;
  const size_t off_rT   = off_rL3 + (size_t)NROWS * 4;
  const size_t off_cand = (off_rT + (size_t)NROWS * 4 + 255) & ~(size_t)255;

  int cap = CAP;
  if (ws_size < off_cand + (size_t)NROWS * cap * 16){
    size_t avail = (ws_size > off_cand) ? (ws_size - off_cand) / ((size_t)NROWS * 16) : 0;
    cap = (int)avail;
  }

  unsigned int* keys = (unsigned int*)(ws + off_keys);
  float*        l3   = (float*)(ws + off_l3);
  unsigned int* h0   = (unsigned int*)(ws + off_h0);
  unsigned int* h1   = (unsigned int*)(ws + off_h1);
  unsigned int* cc   = (unsigned int*)(ws + off_cc);
  unsigned int* pT1  = (unsigned int*)(ws + off_pT1);
  float*        pL3  = (float*)(ws + off_pL3);
  unsigned int* pT2  = (unsigned int*)(ws + off_pT2);
  float*        rL3  = (float*)(ws + off_rL3);
  unsigned int* rT   = (unsigned int*)(ws + off_rT);
  uint4*        cand = (uint4*)(ws + off_cand);

  const int nzero = (int)((zero_end - off_h0) / 4);   // h0, h1, candCount
  k_zero<<<8, 256, 0, stream>>>(h0, nzero);
  k_compute<<<NROWS * K1_BPR, 256, 0, stream>>>(in1, in2, in3, tgt, kdwp,
                                                keys, l3, h0, pT1);
  k_refine<<<NROWS * KR_BPR, 256, 0, stream>>>(keys, h0, frp, h1);
  k_collect<<<NROWS * KC_BPR, 256, 0, stream>>>(keys, l3, h0, h1, frp,
                                                cc, cand, cap, pL3, pT2);
  k_resolve<<<NROWS, 256, 0, stream>>>(h0, h1, frp, cc, cand, cap, rL3, rT);
  k_final<<<1, 256, 0, stream>>>(pT1, pL3, pT2, rL3, rT, frp, out);
}